// Round 8
// baseline (651.632 us; speedup 1.0000x reference)
//
#include <hip/hip_runtime.h>

#define NN 8192
#define HID 256
#define OUT_DIM 64
#define MAX_NNZ 512  // per-row capacity; row nnz ~ Binom(8192,0.03): mean 246, sigma 15.4 -> 17-sigma margin

// clang vector type: __builtin_nontemporal_load requires a real vector type,
// not HIP's float4 class (compile error on gfx950 otherwise).
typedef float f32x4 __attribute__((ext_vector_type(4)));

static __device__ __forceinline__ f32x4 nt_load4(const float* p) {
    return __builtin_nontemporal_load(reinterpret_cast<const f32x4*>(p));
}

// ---------------------------------------------------------------------------
// Tiled f32 GEMM: C[M,N] = act(A[M,K] @ W[K,N] (+ bias)), act = relu if RELU_BIAS
// BM=BN=64, BK=16, 256 threads, 4x4 microtile per thread. No fp32 MFMA on CDNA4,
// so this is vector-ALU; 1.07 GFLOP per GEMM -> ~15-25us each.
// ---------------------------------------------------------------------------
template <bool RELU_BIAS>
__global__ __launch_bounds__(256) void gemm_f32(const float* __restrict__ A,
                                                const float* __restrict__ W,
                                                const float* __restrict__ bias,
                                                float* __restrict__ C,
                                                int M, int N, int K) {
    __shared__ float As[16][68];  // As[k][m], +4 pad
    __shared__ float Bs[16][68];  // Bs[k][n], +4 pad (rows stay 16B aligned)

    const int tid = threadIdx.x;
    const int tx = tid & 15;   // col group
    const int ty = tid >> 4;   // row group
    const int brow = blockIdx.x * 64;
    const int bcol = blockIdx.y * 64;

    float acc[4][4] = {};

    for (int k0 = 0; k0 < K; k0 += 16) {
        {
            const int r = tid >> 2;
            const int c4 = (tid & 3) * 4;
            float4 av = *reinterpret_cast<const float4*>(
                &A[(size_t)(brow + r) * K + k0 + c4]);
            As[c4 + 0][r] = av.x;
            As[c4 + 1][r] = av.y;
            As[c4 + 2][r] = av.z;
            As[c4 + 3][r] = av.w;
        }
        {
            const int kk = tid >> 4;
            const int cc = (tid & 15) * 4;
            float4 bv = *reinterpret_cast<const float4*>(
                &W[(size_t)(k0 + kk) * N + bcol + cc]);
            *reinterpret_cast<float4*>(&Bs[kk][cc]) = bv;
        }
        __syncthreads();

#pragma unroll
        for (int kk = 0; kk < 16; ++kk) {
            float4 a4 = *reinterpret_cast<const float4*>(&As[kk][ty * 4]);
            float4 b4 = *reinterpret_cast<const float4*>(&Bs[kk][tx * 4]);
            const float a[4] = {a4.x, a4.y, a4.z, a4.w};
            const float b[4] = {b4.x, b4.y, b4.z, b4.w};
#pragma unroll
            for (int i = 0; i < 4; ++i)
#pragma unroll
                for (int j = 0; j < 4; ++j) acc[i][j] = fmaf(a[i], b[j], acc[i][j]);
        }
        __syncthreads();
    }

#pragma unroll
    for (int i = 0; i < 4; ++i) {
        const int row = brow + ty * 4 + i;
        const int col = bcol + tx * 4;
        float4 v;
        float r[4];
#pragma unroll
        for (int j = 0; j < 4; ++j) {
            float x = acc[i][j];
            if (RELU_BIAS) x = fmaxf(x + bias[col + j], 0.f);
            r[j] = x;
        }
        v.x = r[0]; v.y = r[1]; v.z = r[2]; v.w = r[3];
        *reinterpret_cast<float4*>(&C[(size_t)row * N + col]) = v;
    }
}

// ---------------------------------------------------------------------------
// Fused SpMM + epilogue, WAVE-PER-ROW (4 rows per 256-thread block, zero
// __syncthreads; wave-local LDS RAW fenced with wave_barrier). Per row i:
//   w_ij = (adj>0 && sim>0) ? adj*sim : 0          (~246 nnz of 8192)
//   t[i,:] = sum_j w_ij * g[j,:]                   (gathers of L2/L3-resident g)
//   feat  = relu(t + b_gcn)
//   out[i,:] = relu(feat @ W_dt + b_dt)
// Compaction is ballot-prefix (deterministic order, no LDS atomics).
// Phase-2 gathers unrolled x8 for MLP (latency-bound on L2/L3 hits).
// ---------------------------------------------------------------------------
__global__ __launch_bounds__(256) void spmm_fused(const float* __restrict__ adj,
                                                  const float* __restrict__ sim,
                                                  const float* __restrict__ g,
                                                  const float* __restrict__ b_gcn,
                                                  const float* __restrict__ W_dt,
                                                  const float* __restrict__ b_dt,
                                                  float* __restrict__ out) {
    __shared__ int s_idx[4][MAX_NNZ];
    __shared__ float s_w[4][MAX_NNZ];
    __shared__ float s_feat[4][HID];

    const int tid = threadIdx.x;
    const int wave = tid >> 6;
    const int lane = tid & 63;
    const int row = blockIdx.x * 4 + wave;
    const size_t rowbase = (size_t)row * NN;
    const unsigned long long lt_mask = (1ull << lane) - 1ull;

    // ---- phase 1: stream row of adj/sim, compact nnz into LDS -------------
    int base = 0;  // wave-uniform running nnz count (ballot is wave-uniform)
#pragma unroll 2
    for (int seg = 0; seg < NN / 256; ++seg) {  // 32 segments of 256 floats
        const int col = seg * 256 + lane * 4;
        f32x4 a4 = nt_load4(&adj[rowbase + col]);
        f32x4 s4 = nt_load4(&sim[rowbase + col]);
        const float av[4] = {a4.x, a4.y, a4.z, a4.w};
        const float sv[4] = {s4.x, s4.y, s4.z, s4.w};
#pragma unroll
        for (int e = 0; e < 4; ++e) {
            const bool hit = (av[e] > 0.f) && (sv[e] > 0.f);
            const unsigned long long m = __ballot(hit);
            if (hit) {
                const int off = base + __popcll(m & lt_mask);
                if (off < MAX_NNZ) {
                    s_idx[wave][off] = col + e;
                    s_w[wave][off] = av[e] * sv[e];
                }
            }
            base += __popcll(m);
        }
    }
    const int cnt = (base < MAX_NNZ) ? base : MAX_NNZ;
    // Fence: lanes now read s_idx/s_w words written by OTHER lanes of this
    // wave. wave_barrier emits no code but stops the scheduler from hoisting
    // the ds_reads above the ds_writes (guide rule #18 class of hazard).
    __builtin_amdgcn_wave_barrier();

    // ---- phase 2: gather rows of g, accumulate 4 h-columns per lane -------
    // Unroll x8: 8 outstanding 1KB gathers per wave; x32 waves/CU resident
    // -> enough MLP to hide ~600cy L2/L3-hit latency.
    float4 acc = {0.f, 0.f, 0.f, 0.f};
    const float* gl = g + lane * 4;  // lane's 16B slice of each 1KB g-row
    int l = 0;
    for (; l + 8 <= cnt; l += 8) {
        int jj[8];
        float ww[8];
        float4 gv[8];
#pragma unroll
        for (int u = 0; u < 8; ++u) {
            jj[u] = s_idx[wave][l + u];
            ww[u] = s_w[wave][l + u];
        }
#pragma unroll
        for (int u = 0; u < 8; ++u)
            gv[u] = *reinterpret_cast<const float4*>(gl + (size_t)jj[u] * HID);
#pragma unroll
        for (int u = 0; u < 8; ++u) {
            acc.x = fmaf(ww[u], gv[u].x, acc.x);
            acc.y = fmaf(ww[u], gv[u].y, acc.y);
            acc.z = fmaf(ww[u], gv[u].z, acc.z);
            acc.w = fmaf(ww[u], gv[u].w, acc.w);
        }
    }
    for (; l + 4 <= cnt; l += 4) {
        int jj[4];
        float ww[4];
        float4 gv[4];
#pragma unroll
        for (int u = 0; u < 4; ++u) {
            jj[u] = s_idx[wave][l + u];
            ww[u] = s_w[wave][l + u];
        }
#pragma unroll
        for (int u = 0; u < 4; ++u)
            gv[u] = *reinterpret_cast<const float4*>(gl + (size_t)jj[u] * HID);
#pragma unroll
        for (int u = 0; u < 4; ++u) {
            acc.x = fmaf(ww[u], gv[u].x, acc.x);
            acc.y = fmaf(ww[u], gv[u].y, acc.y);
            acc.z = fmaf(ww[u], gv[u].z, acc.z);
            acc.w = fmaf(ww[u], gv[u].w, acc.w);
        }
    }
    for (; l < cnt; ++l) {
        const int j = s_idx[wave][l];
        const float w = s_w[wave][l];
        const float4 gv = *reinterpret_cast<const float4*>(gl + (size_t)j * HID);
        acc.x = fmaf(w, gv.x, acc.x); acc.y = fmaf(w, gv.y, acc.y);
        acc.z = fmaf(w, gv.z, acc.z); acc.w = fmaf(w, gv.w, acc.w);
    }

    // ---- phase 3: epilogue (wave-local; fenced LDS RAW, no barriers) ------
    const float4 bg = *reinterpret_cast<const float4*>(&b_gcn[lane * 4]);
    float4 feat;
    feat.x = fmaxf(acc.x + bg.x, 0.f);
    feat.y = fmaxf(acc.y + bg.y, 0.f);
    feat.z = fmaxf(acc.z + bg.z, 0.f);
    feat.w = fmaxf(acc.w + bg.w, 0.f);
    *reinterpret_cast<float4*>(&s_feat[wave][lane * 4]) = feat;
    __builtin_amdgcn_wave_barrier();

    float p = 0.f;
#pragma unroll 8
    for (int h4 = 0; h4 < HID / 4; ++h4) {
        // s_feat read: all 64 lanes same address -> LDS broadcast, no conflict.
        const float4 f4 = *reinterpret_cast<const float4*>(&s_feat[wave][h4 * 4]);
        p = fmaf(f4.x, W_dt[(h4 * 4 + 0) * OUT_DIM + lane], p);
        p = fmaf(f4.y, W_dt[(h4 * 4 + 1) * OUT_DIM + lane], p);
        p = fmaf(f4.z, W_dt[(h4 * 4 + 2) * OUT_DIM + lane], p);
        p = fmaf(f4.w, W_dt[(h4 * 4 + 3) * OUT_DIM + lane], p);
    }
    out[(size_t)row * OUT_DIM + lane] = fmaxf(p + b_dt[lane], 0.f);
}

extern "C" void kernel_launch(void* const* d_in, const int* in_sizes, int n_in,
                              void* d_out, int out_size, void* d_ws, size_t ws_size,
                              hipStream_t stream) {
    const float* h      = (const float*)d_in[0];
    const float* adj    = (const float*)d_in[1];
    const float* simlar = (const float*)d_in[2];
    const float* W_proj = (const float*)d_in[3];
    const float* b_proj = (const float*)d_in[4];
    const float* W_gcn  = (const float*)d_in[5];
    const float* b_gcn  = (const float*)d_in[6];
    const float* W_dt   = (const float*)d_in[7];
    const float* b_dt   = (const float*)d_in[8];
    float* out = (float*)d_out;

    // Workspace: hp (8 MB) + g (8 MB) = 16 MB total.
    (void)ws_size;  // harness preallocates; >= 16 MB required
    float* hp = (float*)d_ws;
    float* g  = (float*)d_ws + (size_t)NN * HID;

    dim3 gemm_grid(NN / 64, HID / 64);  // (128, 4)
    gemm_f32<true><<<gemm_grid, 256, 0, stream>>>(h, W_proj, b_proj, hp, NN, HID, HID);
    gemm_f32<false><<<gemm_grid, 256, 0, stream>>>(hp, W_gcn, nullptr, g, NN, HID, HID);
    spmm_fused<<<NN / 4, 256, 0, stream>>>(adj, simlar, g, b_gcn, W_dt, b_dt, out);
}